// Round 3
// baseline (577.618 us; speedup 1.0000x reference)
//
#include <hip/hip_runtime.h>
#include <cstdint>
#include <cstddef>

// FeedForward: GroupNorm(8) -> conv1x1 C->2C -> GELU(exact) -> conv1x1 2C->C -> +x
// B=16, C=512, L=4096. ALL I/O IS FP32 (per reference). Internal: bf16 MFMA,
// fp32 stats/accum/epilogue.
//
//  k1 gn_stats_partial: partial (sum,sumsq) per (b,g,slice)   [1024 blocks]
//  k2 conv_w:           w1,w2 fp32 -> bf16 once               [2 MiB]
//  per chunk (adaptive NC so ws fits):
//   k3 gn_norm_tr: xnT[(b,l)][c] = norm(x) bf16  (transpose: K=c contiguous)
//   k4 gemm1:      h1T[(b,l)][d] = gelu(xnT . w1^T + b1)  M=CB*4096 N=1024 K=512
//   k5 gemm2:      out[b][c][l]  = x + w2 . h1T^T + b2    M=512 N=CB*4096 K=1024

typedef unsigned short u16;
typedef unsigned int u32;
typedef __attribute__((ext_vector_type(8))) __bf16 bf16x8;
typedef __attribute__((ext_vector_type(4))) float floatx4;

#define BM 128
#define BN 128
#define BKK 64

__device__ __forceinline__ u16 f2bf(float f) {
    union { float f; u32 u; } v; v.f = f;
    u32 u = v.u;
    return (u16)((u + 0x7fffu + ((u >> 16) & 1u)) >> 16);  // RNE
}

// ---------------- kernel 1: partial group stats ----------------
__global__ __launch_bounds__(256) void gn_stats_partial(const float* __restrict__ x,
                                                        float* __restrict__ pstats) {
    const int bx = blockIdx.x;  // bg*8 + slice
    const float4* p = (const float4*)(x + (size_t)(bx >> 3) * 262144 + (size_t)(bx & 7) * 32768);
    float s = 0.f, ss = 0.f;
    for (int i = threadIdx.x; i < 8192; i += 256) {
        float4 v = p[i];
        s += v.x + v.y + v.z + v.w;
        ss += v.x * v.x + v.y * v.y + v.z * v.z + v.w * v.w;
    }
#pragma unroll
    for (int off = 32; off > 0; off >>= 1) {
        s  += __shfl_down(s, off, 64);
        ss += __shfl_down(ss, off, 64);
    }
    __shared__ float rs[8];
    const int wv = threadIdx.x >> 6;
    if ((threadIdx.x & 63) == 0) { rs[wv * 2] = s; rs[wv * 2 + 1] = ss; }
    __syncthreads();
    if (threadIdx.x == 0) {
        pstats[bx * 2]     = rs[0] + rs[2] + rs[4] + rs[6];
        pstats[bx * 2 + 1] = rs[1] + rs[3] + rs[5] + rs[7];
    }
}

// ---------------- kernel 2: weights fp32 -> bf16 ----------------
__global__ __launch_bounds__(256) void conv_w(const float* __restrict__ w1,
                                              const float* __restrict__ w2,
                                              u16* __restrict__ wb) {
    const int idx = (blockIdx.x * 256 + threadIdx.x) * 4;  // < 1048576
    const float4 v = (idx < 524288) ? *(const float4*)(w1 + idx)
                                    : *(const float4*)(w2 + (idx - 524288));
    ushort4 o;
    o.x = f2bf(v.x); o.y = f2bf(v.y); o.z = f2bf(v.z); o.w = f2bf(v.w);
    *(ushort4*)(wb + idx) = o;
}

// ---------------- kernel 3: normalize + transpose (fp32 -> bf16) ----------------
__global__ __launch_bounds__(256) void gn_norm_tr(const float* __restrict__ x,
                                                  const float* __restrict__ gamma,
                                                  const float* __restrict__ beta,
                                                  const float* __restrict__ pstats,
                                                  u16* __restrict__ xnT, int b0) {
    __shared__ u16 T[64][72];  // [l][c], c-groups XOR-swizzled by (l>>3)&7
    const int bx = blockIdx.x;
    const int lt = bx & 63, ct = (bx >> 6) & 7, bl = bx >> 9;
    const int b = b0 + bl;
    const int c0 = ct * 64, l0 = lt * 64;
    const int g = c0 >> 6;   // tile spans exactly one group (64 c per group)
    float S = 0.f, SS = 0.f;
#pragma unroll
    for (int s2 = 0; s2 < 8; ++s2) {
        S  += pstats[((b * 8 + g) * 8 + s2) * 2];
        SS += pstats[((b * 8 + g) * 8 + s2) * 2 + 1];
    }
    const float inv = 1.f / 262144.f;
    const float mean = S * inv;
    const float var = SS * inv - mean * mean;  // population var (jnp.var)
    const float rstd = rsqrtf(var + 1e-5f);

    const int t = threadIdx.x;
    const int cl = t >> 3;          // 0..31
    const int lo = (t & 7) * 8;     // 8 l's per thread
    const int sw = t & 7;           // == (l>>3)&7 for all 8 l's this thread owns
#pragma unroll
    for (int h = 0; h < 2; ++h) {
        const int c = c0 + cl + h * 32;
        const float sc = rstd * gamma[c];
        const float sh = beta[c] - mean * sc;
        const float* src = x + ((size_t)(b * 512 + c) * 4096 + l0 + lo);
        float4 a = *(const float4*)src;
        float4 bq = *(const float4*)(src + 4);
        float vv[8] = {a.x, a.y, a.z, a.w, bq.x, bq.y, bq.z, bq.w};
        const int ccol = cl + h * 32;
        const int cg = ccol >> 3, cr = ccol & 7;
#pragma unroll
        for (int q = 0; q < 8; ++q)
            T[lo + q][((cg ^ sw) << 3) + cr] = f2bf(fmaf(vv[q], sc, sh));
    }
    __syncthreads();
    const int ll = t >> 3;
    const int co = (t & 7) * 8, cog = t & 7;
#pragma unroll
    for (int h = 0; h < 2; ++h) {
        const int l = ll + h * 32;
        const uint4* srcv = (const uint4*)&T[l][(cog ^ ((l >> 3) & 7)) << 3];
        *(uint4*)(xnT + ((size_t)(bl * 4096 + l0 + l) * 512 + c0 + co)) = *srcv;
    }
}

// ---------------- GEMM core (gemm_bt): C[m][n] = sum_k A[m][k]*B[n][k] ----------------
// LDS: tile[row][colgrp], colgrp = global_kgrp ^ (row&7), colgrp = 8 bf16 (16B).
__device__ __forceinline__ void gemm_core(const u16* __restrict__ Ag,  // [*][K] bf16
                                          const u16* __restrict__ Bg,  // [*][K] bf16
                                          int K, floatx4 acc[4][4],
                                          u16* lA, u16* lB,
                                          int wm, int wn, int fr, int quad) {
    const int t = threadIdx.x;
    uint4* lAv = (uint4*)lA;
    uint4* lBv = (uint4*)lB;
    for (int kt = 0; kt < K; kt += BKK) {
        uint4 va[4], vb[4];
#pragma unroll
        for (int s = 0; s < 4; ++s) {
            int idx = s * 256 + t;
            int row = idx >> 3, col = idx & 7;
            va[s] = *(const uint4*)(Ag + (size_t)row * K + kt + col * 8);
            vb[s] = *(const uint4*)(Bg + (size_t)row * K + kt + col * 8);
        }
#pragma unroll
        for (int s = 0; s < 4; ++s) {
            int idx = s * 256 + t;
            int row = idx >> 3, col = idx & 7;
            lAv[row * 8 + (col ^ (row & 7))] = va[s];
            lBv[row * 8 + (col ^ (row & 7))] = vb[s];
        }
        __syncthreads();
#pragma unroll
        for (int kk = 0; kk < BKK; kk += 32) {
            bf16x8 af[4], bb[4];
#pragma unroll
            for (int i = 0; i < 4; ++i) {
                int row = wm + i * 16 + fr;
                int kg = ((kk >> 3) + quad) ^ (fr & 7);
                af[i] = *(const bf16x8*)(lA + row * BKK + kg * 8);
            }
#pragma unroll
            for (int j = 0; j < 4; ++j) {
                int row = wn + j * 16 + fr;
                int kg = ((kk >> 3) + quad) ^ (fr & 7);
                bb[j] = *(const bf16x8*)(lB + row * BKK + kg * 8);
            }
#pragma unroll
            for (int i = 0; i < 4; ++i)
#pragma unroll
                for (int j = 0; j < 4; ++j)
                    acc[i][j] = __builtin_amdgcn_mfma_f32_16x16x32_bf16(af[i], bb[j], acc[i][j], 0, 0, 0);
        }
        __syncthreads();
    }
}

// ---------------- kernel 4: GEMM1 + bias + exact GELU -> h1T (bf16) ----------------
__global__ __launch_bounds__(256) void gemm1(const u16* __restrict__ xnT,
                                             const u16* __restrict__ w1b,
                                             const float* __restrict__ b1,
                                             u16* __restrict__ h1T) {
    __shared__ uint4 lAq[BM * BKK / 8], lBq[BN * BKK / 8];
    u16* lA = (u16*)lAq; u16* lB = (u16*)lBq;
    const int bx = blockIdx.x;
    const int nt = bx & 7;    // 8 n-tiles of w1 rows
    const int mt = bx >> 3;   // local m-tile
    const int t = threadIdx.x, lane = t & 63, wv = t >> 6;
    const int wm = (wv & 1) * 64, wn = (wv >> 1) * 64;
    const int fr = lane & 15, quad = lane >> 4;
    floatx4 acc[4][4];
#pragma unroll
    for (int i = 0; i < 4; ++i)
#pragma unroll
        for (int j = 0; j < 4; ++j) acc[i][j] = (floatx4){0.f, 0.f, 0.f, 0.f};

    gemm_core(xnT + (size_t)(mt * BM) * 512, w1b + (size_t)(nt * BN) * 512, 512,
              acc, lA, lB, wm, wn, fr, quad);

    const int mbase = mt * BM + wm + quad * 4;
    const int nbase = nt * BN + wn + fr;
#pragma unroll
    for (int j = 0; j < 4; ++j) {
        const int n = nbase + j * 16;
        const float bv = b1[n];
#pragma unroll
        for (int i = 0; i < 4; ++i) {
#pragma unroll
            for (int r = 0; r < 4; ++r) {
                const int m = mbase + i * 16 + r;
                float v = acc[i][j][r] + bv;
                v = 0.5f * v * (1.0f + erff(v * 0.70710678118654752f));
                h1T[(size_t)m * 1024 + n] = f2bf(v);
            }
        }
    }
}

// ---------------- kernel 5: GEMM2 + bias + residual -> out (fp32) ----------------
__global__ __launch_bounds__(256) void gemm2(const u16* __restrict__ w2b,
                                             const u16* __restrict__ h1T,
                                             const float* __restrict__ b2,
                                             const float* __restrict__ x,
                                             float* __restrict__ out, int b0) {
    __shared__ uint4 lAq[BM * BKK / 8], lBq[BN * BKK / 8];
    u16* lA = (u16*)lAq; u16* lB = (u16*)lBq;
    const int bx = blockIdx.x;
    const int mt = bx & 3;     // 4 m-tiles (w2 rows)
    const int nt = bx >> 2;    // local n-tile
    const int t = threadIdx.x, lane = t & 63, wv = t >> 6;
    const int wm = (wv & 1) * 64, wn = (wv >> 1) * 64;
    const int fr = lane & 15, quad = lane >> 4;
    floatx4 acc[4][4];
#pragma unroll
    for (int i = 0; i < 4; ++i)
#pragma unroll
        for (int j = 0; j < 4; ++j) acc[i][j] = (floatx4){0.f, 0.f, 0.f, 0.f};

    gemm_core(w2b + (size_t)(mt * BM) * 1024, h1T + (size_t)(nt * BN) * 1024, 1024,
              acc, lA, lB, wm, wn, fr, quad);

    const int n0g = b0 * 4096 + nt * BN;  // global flat (b,l); tiles never straddle b
    const int b = n0g >> 12;
    const int l_base = n0g & 4095;
    const int mbase = mt * BM + wm + quad * 4;
#pragma unroll
    for (int i = 0; i < 4; ++i) {
#pragma unroll
        for (int r = 0; r < 4; ++r) {
            const int m = mbase + i * 16 + r;
            const float bv = b2[m];
            const size_t rowoff = ((size_t)(b * 512 + m)) * 4096 + l_base;
#pragma unroll
            for (int j = 0; j < 4; ++j) {
                const int lcol = wn + j * 16 + fr;
                out[rowoff + lcol] = acc[i][j][r] + bv + x[rowoff + lcol];
            }
        }
    }
}

extern "C" void kernel_launch(void* const* d_in, const int* in_sizes, int n_in,
                              void* d_out, int out_size, void* d_ws, size_t ws_size,
                              hipStream_t stream) {
    const float* x     = (const float*)d_in[0];
    const float* gamma = (const float*)d_in[1];
    const float* beta  = (const float*)d_in[2];
    const float* w1    = (const float*)d_in[3];
    const float* b1    = (const float*)d_in[4];
    const float* w2    = (const float*)d_in[5];
    const float* b2    = (const float*)d_in[6];
    float* out = (float*)d_out;

    char* ws = (char*)d_ws;
    float* pstats = (float*)ws;                    // 8 KB used
    u16* wb = (u16*)(ws + 65536);                  // 2 MiB: w1b then w2b
    char* chunkbase = ws + 65536 + (2u << 20);
    const size_t fixed = 65536 + (2u << 20);

    // choose smallest chunk count NC so xnT+h1T fit in ws
    const size_t per = (size_t)192 * 1024 * 1024;  // NC=1: 64 MiB xnT + 128 MiB h1T
    int NC = 16;
    if      (ws_size >= fixed + per)      NC = 1;
    else if (ws_size >= fixed + per / 2)  NC = 2;
    else if (ws_size >= fixed + per / 4)  NC = 4;
    else if (ws_size >= fixed + per / 8)  NC = 8;
    const int CB = 16 / NC;                        // batches per chunk
    u16* xnT = (u16*)chunkbase;
    u16* h1T = (u16*)(chunkbase + (size_t)CB * 4096 * 512 * 2);

    gn_stats_partial<<<1024, 256, 0, stream>>>(x, pstats);
    conv_w<<<1024, 256, 0, stream>>>(w1, w2, wb);
    for (int ch = 0; ch < NC; ++ch) {
        const int b0 = ch * CB;
        gn_norm_tr<<<CB * 512, 256, 0, stream>>>(x, gamma, beta, pstats, xnT, b0);
        gemm1<<<CB * 32 * 8, 256, 0, stream>>>(xnT, wb, b1, h1T);
        gemm2<<<CB * 32 * 4, 256, 0, stream>>>(wb + 524288, h1T, b2, x, out, b0);
    }
}

// Round 4
// 555.025 us; speedup vs baseline: 1.0407x; 1.0407x over previous
//
#include <hip/hip_runtime.h>
#include <cstdint>
#include <cstddef>

// FeedForward: GroupNorm(8) -> conv1x1 C->2C -> GELU(exact) -> conv1x1 2C->C -> +x
// B=16, C=512, L=4096. ALL I/O FP32. Internal: bf16 MFMA, fp32 accum.
//
// R4 changes vs R3 (passing, 577us):
//  - gemm_core staging: manual uint4->ds_write  ==>  global_load_lds width=16
//    (m97 structure; XOR k-swizzle on GLOBAL address, LDS lane-linear).
//  - XCD-aware block swizzle in both GEMMs: blocks sharing the large operand
//    tile now share bx%8 (same XCD's L2) and are adjacent in dispatch.
//    Fixes gemm1's 266MB (4x) overfetch of xnT / gemm2's h1T overfetch.

typedef unsigned short u16;
typedef unsigned int u32;
typedef __attribute__((ext_vector_type(8))) __bf16 bf16x8;
typedef __attribute__((ext_vector_type(4))) float floatx4;

#define BM 128
#define BN 128
#define BKK 64

__device__ __forceinline__ u16 f2bf(float f) {
    union { float f; u32 u; } v; v.f = f;
    u32 u = v.u;
    return (u16)((u + 0x7fffu + ((u >> 16) & 1u)) >> 16);  // RNE
}

__device__ __forceinline__ void async_cp16(u16* lds, const u16* g) {
    __builtin_amdgcn_global_load_lds(
        (const __attribute__((address_space(1))) u32*)g,
        (__attribute__((address_space(3))) u32*)lds,
        16, 0, 0);
}

// ---------------- kernel 1: partial group stats ----------------
__global__ __launch_bounds__(256) void gn_stats_partial(const float* __restrict__ x,
                                                        float* __restrict__ pstats) {
    const int bx = blockIdx.x;  // bg*8 + slice
    const float4* p = (const float4*)(x + (size_t)(bx >> 3) * 262144 + (size_t)(bx & 7) * 32768);
    float s = 0.f, ss = 0.f;
    for (int i = threadIdx.x; i < 8192; i += 256) {
        float4 v = p[i];
        s += v.x + v.y + v.z + v.w;
        ss += v.x * v.x + v.y * v.y + v.z * v.z + v.w * v.w;
    }
#pragma unroll
    for (int off = 32; off > 0; off >>= 1) {
        s  += __shfl_down(s, off, 64);
        ss += __shfl_down(ss, off, 64);
    }
    __shared__ float rs[8];
    const int wv = threadIdx.x >> 6;
    if ((threadIdx.x & 63) == 0) { rs[wv * 2] = s; rs[wv * 2 + 1] = ss; }
    __syncthreads();
    if (threadIdx.x == 0) {
        pstats[bx * 2]     = rs[0] + rs[2] + rs[4] + rs[6];
        pstats[bx * 2 + 1] = rs[1] + rs[3] + rs[5] + rs[7];
    }
}

// ---------------- kernel 2: weights fp32 -> bf16 ----------------
__global__ __launch_bounds__(256) void conv_w(const float* __restrict__ w1,
                                              const float* __restrict__ w2,
                                              u16* __restrict__ wb) {
    const int idx = (blockIdx.x * 256 + threadIdx.x) * 4;  // < 1048576
    const float4 v = (idx < 524288) ? *(const float4*)(w1 + idx)
                                    : *(const float4*)(w2 + (idx - 524288));
    ushort4 o;
    o.x = f2bf(v.x); o.y = f2bf(v.y); o.z = f2bf(v.z); o.w = f2bf(v.w);
    *(ushort4*)(wb + idx) = o;
}

// ---------------- kernel 3: normalize + transpose (fp32 -> bf16) ----------------
__global__ __launch_bounds__(256) void gn_norm_tr(const float* __restrict__ x,
                                                  const float* __restrict__ gamma,
                                                  const float* __restrict__ beta,
                                                  const float* __restrict__ pstats,
                                                  u16* __restrict__ xnT, int b0) {
    __shared__ u16 T[64][72];  // [l][c], c-groups XOR-swizzled by (l>>3)&7
    const int bx = blockIdx.x;
    const int lt = bx & 63, ct = (bx >> 6) & 7, bl = bx >> 9;
    const int b = b0 + bl;
    const int c0 = ct * 64, l0 = lt * 64;
    const int g = c0 >> 6;   // tile spans exactly one group
    float S = 0.f, SS = 0.f;
#pragma unroll
    for (int s2 = 0; s2 < 8; ++s2) {
        S  += pstats[((b * 8 + g) * 8 + s2) * 2];
        SS += pstats[((b * 8 + g) * 8 + s2) * 2 + 1];
    }
    const float inv = 1.f / 262144.f;
    const float mean = S * inv;
    const float var = SS * inv - mean * mean;  // population var (jnp.var)
    const float rstd = rsqrtf(var + 1e-5f);

    const int t = threadIdx.x;
    const int cl = t >> 3;          // 0..31
    const int lo = (t & 7) * 8;     // 8 l's per thread
    const int sw = t & 7;           // == (l>>3)&7 for this thread's l's
#pragma unroll
    for (int h = 0; h < 2; ++h) {
        const int c = c0 + cl + h * 32;
        const float sc = rstd * gamma[c];
        const float sh = beta[c] - mean * sc;
        const float* src = x + ((size_t)(b * 512 + c) * 4096 + l0 + lo);
        float4 a = *(const float4*)src;
        float4 bq = *(const float4*)(src + 4);
        float vv[8] = {a.x, a.y, a.z, a.w, bq.x, bq.y, bq.z, bq.w};
        const int ccol = cl + h * 32;
        const int cg = ccol >> 3, cr = ccol & 7;
#pragma unroll
        for (int q = 0; q < 8; ++q)
            T[lo + q][((cg ^ sw) << 3) + cr] = f2bf(fmaf(vv[q], sc, sh));
    }
    __syncthreads();
    const int ll = t >> 3;
    const int co = (t & 7) * 8, cog = t & 7;
#pragma unroll
    for (int h = 0; h < 2; ++h) {
        const int l = ll + h * 32;
        const uint4* srcv = (const uint4*)&T[l][(cog ^ ((l >> 3) & 7)) << 3];
        *(uint4*)(xnT + ((size_t)(bl * 4096 + l0 + l) * 512 + c0 + co)) = *srcv;
    }
}

// ---------------- GEMM core (gemm_bt): C[m][n] = sum_k A[m][k]*B[n][k] ----------------
// Staging: global_load_lds width=16. LDS slot idx holds global k-group
// (idx&7)^(row&7)  (XOR baked into the GLOBAL fetch address; LDS lane-linear).
// Read for (row, kgroup g) -> slot col g^(row&7); row&7 == fr&7 here.
__device__ __forceinline__ void gemm_core(const u16* __restrict__ Ag,  // [*][K] bf16
                                          const u16* __restrict__ Bg,  // [*][K] bf16
                                          int K, floatx4 acc[4][4],
                                          u16* lA, u16* lB,
                                          int wm, int wn, int fr, int quad) {
    const int t = threadIdx.x;
    for (int kt = 0; kt < K; kt += BKK) {
#pragma unroll
        for (int s = 0; s < 4; ++s) {
            int idx = s * 256 + t;
            int row = idx >> 3;
            int kg = (idx & 7) ^ (row & 7);
            async_cp16(lA + idx * 8, Ag + (size_t)row * K + kt + kg * 8);
        }
#pragma unroll
        for (int s = 0; s < 4; ++s) {
            int idx = s * 256 + t;
            int row = idx >> 3;
            int kg = (idx & 7) ^ (row & 7);
            async_cp16(lB + idx * 8, Bg + (size_t)row * K + kt + kg * 8);
        }
        __syncthreads();  // vmcnt(0) drain before s_barrier (compiler-emitted)
#pragma unroll
        for (int kk = 0; kk < BKK; kk += 32) {
            bf16x8 af[4], bb[4];
#pragma unroll
            for (int i = 0; i < 4; ++i) {
                int row = wm + i * 16 + fr;
                int kg = ((kk >> 3) + quad) ^ (fr & 7);
                af[i] = *(const bf16x8*)(lA + row * BKK + kg * 8);
            }
#pragma unroll
            for (int j = 0; j < 4; ++j) {
                int row = wn + j * 16 + fr;
                int kg = ((kk >> 3) + quad) ^ (fr & 7);
                bb[j] = *(const bf16x8*)(lB + row * BKK + kg * 8);
            }
#pragma unroll
            for (int i = 0; i < 4; ++i)
#pragma unroll
                for (int j = 0; j < 4; ++j)
                    acc[i][j] = __builtin_amdgcn_mfma_f32_16x16x32_bf16(af[i], bb[j], acc[i][j], 0, 0, 0);
        }
        __syncthreads();
    }
}

// ---------------- kernel 4: GEMM1 + bias + exact GELU -> h1T (bf16) ----------------
__global__ __launch_bounds__(256) void gemm1(const u16* __restrict__ xnT,
                                             const u16* __restrict__ w1b,
                                             const float* __restrict__ b1,
                                             u16* __restrict__ h1T) {
    __shared__ uint4 lAq[BM * BKK / 8], lBq[BN * BKK / 8];
    u16* lA = (u16*)lAq; u16* lB = (u16*)lBq;
    const int bx = blockIdx.x;
    // XCD swizzle: mt%8 == bx%8, the 8 nt's of one mt adjacent in dispatch.
    const int nt = (bx >> 3) & 7;
    const int mt = (bx & 7) | ((bx >> 6) << 3);
    const int t = threadIdx.x, lane = t & 63, wv = t >> 6;
    const int wm = (wv & 1) * 64, wn = (wv >> 1) * 64;
    const int fr = lane & 15, quad = lane >> 4;
    floatx4 acc[4][4];
#pragma unroll
    for (int i = 0; i < 4; ++i)
#pragma unroll
        for (int j = 0; j < 4; ++j) acc[i][j] = (floatx4){0.f, 0.f, 0.f, 0.f};

    gemm_core(xnT + (size_t)(mt * BM) * 512, w1b + (size_t)(nt * BN) * 512, 512,
              acc, lA, lB, wm, wn, fr, quad);

    const int mbase = mt * BM + wm + quad * 4;
    const int nbase = nt * BN + wn + fr;
#pragma unroll
    for (int j = 0; j < 4; ++j) {
        const int n = nbase + j * 16;
        const float bv = b1[n];
#pragma unroll
        for (int i = 0; i < 4; ++i) {
#pragma unroll
            for (int r = 0; r < 4; ++r) {
                const int m = mbase + i * 16 + r;
                float v = acc[i][j][r] + bv;
                v = 0.5f * v * (1.0f + erff(v * 0.70710678118654752f));
                h1T[(size_t)m * 1024 + n] = f2bf(v);
            }
        }
    }
}

// ---------------- kernel 5: GEMM2 + bias + residual -> out (fp32) ----------------
__global__ __launch_bounds__(256) void gemm2(const u16* __restrict__ w2b,
                                             const u16* __restrict__ h1T,
                                             const float* __restrict__ b2,
                                             const float* __restrict__ x,
                                             float* __restrict__ out, int b0) {
    __shared__ uint4 lAq[BM * BKK / 8], lBq[BN * BKK / 8];
    u16* lA = (u16*)lAq; u16* lB = (u16*)lBq;
    const int bx = blockIdx.x;
    // XCD swizzle: nt%8 == bx%8, the 4 mt's of one nt adjacent in dispatch.
    const int mt = (bx >> 3) & 3;
    const int nt = (bx & 7) | ((bx >> 5) << 3);
    const int t = threadIdx.x, lane = t & 63, wv = t >> 6;
    const int wm = (wv & 1) * 64, wn = (wv >> 1) * 64;
    const int fr = lane & 15, quad = lane >> 4;
    floatx4 acc[4][4];
#pragma unroll
    for (int i = 0; i < 4; ++i)
#pragma unroll
        for (int j = 0; j < 4; ++j) acc[i][j] = (floatx4){0.f, 0.f, 0.f, 0.f};

    gemm_core(w2b + (size_t)(mt * BM) * 1024, h1T + (size_t)(nt * BN) * 1024, 1024,
              acc, lA, lB, wm, wn, fr, quad);

    const int n0g = b0 * 4096 + nt * BN;  // global flat (b,l); tiles never straddle b
    const int b = n0g >> 12;
    const int l_base = n0g & 4095;
    const int mbase = mt * BM + wm + quad * 4;
#pragma unroll
    for (int i = 0; i < 4; ++i) {
#pragma unroll
        for (int r = 0; r < 4; ++r) {
            const int m = mbase + i * 16 + r;
            const float bv = b2[m];
            const size_t rowoff = ((size_t)(b * 512 + m)) * 4096 + l_base;
#pragma unroll
            for (int j = 0; j < 4; ++j) {
                const int lcol = wn + j * 16 + fr;
                out[rowoff + lcol] = acc[i][j][r] + bv + x[rowoff + lcol];
            }
        }
    }
}

extern "C" void kernel_launch(void* const* d_in, const int* in_sizes, int n_in,
                              void* d_out, int out_size, void* d_ws, size_t ws_size,
                              hipStream_t stream) {
    const float* x     = (const float*)d_in[0];
    const float* gamma = (const float*)d_in[1];
    const float* beta  = (const float*)d_in[2];
    const float* w1    = (const float*)d_in[3];
    const float* b1    = (const float*)d_in[4];
    const float* w2    = (const float*)d_in[5];
    const float* b2    = (const float*)d_in[6];
    float* out = (float*)d_out;

    char* ws = (char*)d_ws;
    float* pstats = (float*)ws;                    // 8 KB used
    u16* wb = (u16*)(ws + 65536);                  // 2 MiB: w1b then w2b
    char* chunkbase = ws + 65536 + (2u << 20);
    const size_t fixed = 65536 + (2u << 20);

    // choose smallest chunk count NC so xnT+h1T fit in ws
    const size_t per = (size_t)192 * 1024 * 1024;  // NC=1: 64 MiB xnT + 128 MiB h1T
    int NC = 16;
    if      (ws_size >= fixed + per)      NC = 1;
    else if (ws_size >= fixed + per / 2)  NC = 2;
    else if (ws_size >= fixed + per / 4)  NC = 4;
    else if (ws_size >= fixed + per / 8)  NC = 8;
    const int CB = 16 / NC;                        // batches per chunk
    u16* xnT = (u16*)chunkbase;
    u16* h1T = (u16*)(chunkbase + (size_t)CB * 4096 * 512 * 2);

    gn_stats_partial<<<1024, 256, 0, stream>>>(x, pstats);
    conv_w<<<1024, 256, 0, stream>>>(w1, w2, wb);
    for (int ch = 0; ch < NC; ++ch) {
        const int b0 = ch * CB;
        gn_norm_tr<<<CB * 512, 256, 0, stream>>>(x, gamma, beta, pstats, xnT, b0);
        gemm1<<<CB * 32 * 8, 256, 0, stream>>>(xnT, wb, b1, h1T);
        gemm2<<<CB * 32 * 4, 256, 0, stream>>>(wb + 524288, h1T, b2, x, out, b0);
    }
}